// Round 9
// baseline (498.255 us; speedup 1.0000x reference)
//
#include <hip/hip_runtime.h>

#define HID 1024
#define HEADS 16
#define HD 64
#define TAB 129
#define QSTR 136   // padded qtab row stride (ushorts, 16B-aligned rows)
#define BATCH 8
#define SEQ 512

typedef unsigned int uint;
typedef unsigned short ushort;
typedef __attribute__((ext_vector_type(4))) float f32x4;
typedef __attribute__((ext_vector_type(8))) __bf16 bf16x8;

// ---------------------------------------------------------------------------
// bf16 helpers
// ---------------------------------------------------------------------------
__device__ __forceinline__ ushort f2b(float x) {
    uint b = __float_as_uint(x);
    uint r = (b + 0x7fffu + ((b >> 16) & 1u)) >> 16;
    return (ushort)r;
}
__device__ __forceinline__ uint pk(float lo, float hi) {
    return (uint)f2b(lo) | ((uint)f2b(hi) << 16);
}
__device__ __forceinline__ float b2f(ushort u) {
    return __uint_as_float(((uint)u) << 16);
}
__device__ __forceinline__ void unpack8(uint4 u, float* f) {
    f[0] = __uint_as_float(u.x << 16); f[1] = __uint_as_float(u.x & 0xffff0000u);
    f[2] = __uint_as_float(u.y << 16); f[3] = __uint_as_float(u.y & 0xffff0000u);
    f[4] = __uint_as_float(u.z << 16); f[5] = __uint_as_float(u.z & 0xffff0000u);
    f[6] = __uint_as_float(u.w << 16); f[7] = __uint_as_float(u.w & 0xffff0000u);
}
union U16x8 { uint u[4]; bf16x8 v; ushort s[8]; uint4 q; };
__device__ __forceinline__ bf16x8 pack8(float a0, float a1, float a2, float a3,
                                        float a4, float a5, float a6, float a7) {
    U16x8 r;
    r.u[0] = pk(a0, a1); r.u[1] = pk(a2, a3);
    r.u[2] = pk(a4, a5); r.u[3] = pk(a6, a7);
    return r.v;
}

// keep-alive sinks (rule #17): force loads to happen without using results
__device__ __forceinline__ void sink8(bf16x8 v) {
    U16x8 u; u.v = v;
    asm volatile("" :: "v"(u.u[0]), "v"(u.u[1]), "v"(u.u[2]), "v"(u.u[3]));
}
__device__ __forceinline__ void sink4i(int4 v) {
    asm volatile("" :: "v"(v.x), "v"(v.y), "v"(v.z), "v"(v.w));
}

#define GL16(gp, lp) __builtin_amdgcn_global_load_lds( \
    (const __attribute__((address_space(1))) void*)(gp), \
    (__attribute__((address_space(3))) void*)(lp), 16, 0, 0)

// LDS-only barrier: order DS ops, keep prefetched VMEM in flight
#define LDS_BARRIER() do { \
        asm volatile("s_waitcnt lgkmcnt(0)" ::: "memory"); \
        __builtin_amdgcn_s_barrier(); \
    } while (0)

// ---------------------------------------------------------------------------
// convert fp32 -> bf16
// ---------------------------------------------------------------------------
struct ConvArgs { const float* src[7]; ushort* dst[7]; };

__global__ __launch_bounds__(256) void convert_bf16(ConvArgs ca) {
    int bid = blockIdx.x;
    int ti, lb;
    if (bid < 6144) { ti = bid >> 11; lb = bid & 2047; }
    else { int r = bid - 6144; ti = 3 + (r >> 9); lb = r & 511; }
    const float* s = ca.src[ti] + (size_t)lb * 2048 + (threadIdx.x << 3);
    ushort*      d = ca.dst[ti] + (size_t)lb * 2048 + (threadIdx.x << 3);
    float4 a = *(const float4*)s;
    float4 c = *(const float4*)(s + 4);
    uint4 u;
    u.x = pk(a.x, a.y); u.y = pk(a.z, a.w);
    u.z = pk(c.x, c.y); u.w = pk(c.z, c.w);
    *(uint4*)d = u;
}

// ---------------------------------------------------------------------------
// bf16 MFMA GEMM (unchanged): C_z = A_z @ W_z^T + bias_z
// ---------------------------------------------------------------------------
struct GemmArgs {
    const ushort* A[3];
    const ushort* W[3];
    const float*  bias[3];
    float*        Cf[3];
    ushort*       Cb[3];
};

__global__ __launch_bounds__(256) void gemm_bf16(GemmArgs ga, int M, int N, int K) {
    __shared__ ushort As[2][128 * 32];
    __shared__ ushort Bs[2][128 * 32];
    const int z = blockIdx.z;
    const ushort* A = ga.A[z];
    const ushort* W = ga.W[z];
    const int tid = threadIdx.x;
    const int m0 = blockIdx.y * 128;
    const int n0 = blockIdx.x * 128;

    const int w  = tid >> 6;
    const int l  = tid & 63;
    const int lr = l & 15;
    const int lg = l >> 4;
    const int wm = w >> 1;
    const int wn = w & 1;

    const int sr = tid >> 2;
    const int sc = tid & 3;
    const int g  = sc ^ ((sr >> 1) & 3);
    const ushort* Ag0 = A + (size_t)(m0 + sr)      * K + g * 8;
    const ushort* Ag1 = A + (size_t)(m0 + sr + 64) * K + g * 8;
    const ushort* Wg0 = W + (size_t)(n0 + sr)      * K + g * 8;
    const ushort* Wg1 = W + (size_t)(n0 + sr + 64) * K + g * 8;

    f32x4 acc[4][4];
#pragma unroll
    for (int mt = 0; mt < 4; ++mt)
#pragma unroll
        for (int nt = 0; nt < 4; ++nt) acc[mt][nt] = (f32x4){0.f, 0.f, 0.f, 0.f};

#define STAGE(buf, k0) do { \
        GL16(Ag0 + (k0), &As[buf][w * 512]); \
        GL16(Ag1 + (k0), &As[buf][2048 + w * 512]); \
        GL16(Wg0 + (k0), &Bs[buf][w * 512]); \
        GL16(Wg1 + (k0), &Bs[buf][2048 + w * 512]); \
    } while (0)

    const int swz = (lr >> 1) & 3;
#define COMPUTE(buf) do { \
        bf16x8 af[4], bf[4]; \
        _Pragma("unroll") \
        for (int mt = 0; mt < 4; ++mt) \
            af[mt] = *(const bf16x8*)&As[buf][(wm * 64 + mt * 16 + lr) * 32 + (lg ^ swz) * 8]; \
        _Pragma("unroll") \
        for (int nt = 0; nt < 4; ++nt) \
            bf[nt] = *(const bf16x8*)&Bs[buf][(wn * 64 + nt * 16 + lr) * 32 + (lg ^ swz) * 8]; \
        _Pragma("unroll") \
        for (int mt = 0; mt < 4; ++mt) \
            _Pragma("unroll") \
            for (int nt = 0; nt < 4; ++nt) \
                acc[mt][nt] = __builtin_amdgcn_mfma_f32_16x16x32_bf16(af[mt], bf[nt], acc[mt][nt], 0, 0, 0); \
    } while (0)

    STAGE(0, 0);
    __syncthreads();
    const int nk = K / 32;
    for (int t = 0; t < nk - 1; ++t) {
        STAGE((t + 1) & 1, (size_t)(t + 1) * 32);
        COMPUTE(t & 1);
        __syncthreads();
    }
    COMPUTE((nk - 1) & 1);

    const float* bias = ga.bias[z];
    float bv[4];
#pragma unroll
    for (int nt = 0; nt < 4; ++nt) bv[nt] = bias[n0 + wn * 64 + nt * 16 + lr];
    float*  Cf = ga.Cf[z];
    ushort* Cb = ga.Cb[z];
    if (Cf) {
#pragma unroll
        for (int mt = 0; mt < 4; ++mt)
#pragma unroll
            for (int r4 = 0; r4 < 4; ++r4) {
                size_t m = m0 + wm * 64 + mt * 16 + lg * 4 + r4;
                float* crow = Cf + m * N + n0 + wn * 64 + lr;
#pragma unroll
                for (int nt = 0; nt < 4; ++nt)
                    crow[nt * 16] = acc[mt][nt][r4] + bv[nt];
            }
    } else {
#pragma unroll
        for (int mt = 0; mt < 4; ++mt)
#pragma unroll
            for (int r4 = 0; r4 < 4; ++r4) {
                size_t m = m0 + wm * 64 + mt * 16 + lg * 4 + r4;
                ushort* crow = Cb + m * N + n0 + wn * 64 + lr;
#pragma unroll
                for (int nt = 0; nt < 4; ++nt)
                    crow[nt * 16] = f2b(acc[mt][nt][r4] + bv[nt]);
            }
    }
#undef STAGE
#undef COMPUTE
}

// ---------------------------------------------------------------------------
// qtab kernel (unchanged)
// ---------------------------------------------------------------------------
__global__ __launch_bounds__(256) void qtab_kernel(const ushort* __restrict__ q4,
                                                   const float* __restrict__ table_k,
                                                   ushort* __restrict__ qtab) {
    __shared__ float qs[64][68];
    __shared__ float tk[TAB][68];
    const int tid = threadIdx.x;
    const int q0 = blockIdx.x * 64;
    const int h  = blockIdx.y;
    const int b  = blockIdx.z;
    for (int f = tid; f < 512; f += 256) {
        int r  = f >> 3;
        int dd = (f & 7) << 3;
        uint4 u = *(const uint4*)&q4[((size_t)(b*SEQ + q0 + r)) * HID + h*HD + dd];
        float f8[8];
        unpack8(u, f8);
#pragma unroll
        for (int j = 0; j < 8; ++j) qs[r][dd + j] = f8[j];
    }
    for (int f = tid; f < TAB*16; f += 256) {
        int t  = f >> 4;
        int dd = (f & 15) << 2;
        *(float4*)&tk[t][dd] = *(const float4*)&table_k[t*HD + dd];
    }
    __syncthreads();
    const int tq = tid >> 2;
    const int tg = tid & 3;
    ushort* outrow = qtab + ((size_t)(b*HEADS + h) * SEQ + q0 + tq) * QSTR;
    for (int t = tg; t < TAB; t += 4) {
        float s = 0.f;
#pragma unroll
        for (int d = 0; d < HD; d += 4) {
            float4 qa = *(const float4*)&qs[tq][d];
            float4 ta = *(const float4*)&tk[t][d];
            s = fmaf(qa.x, ta.x, s); s = fmaf(qa.y, ta.y, s);
            s = fmaf(qa.z, ta.z, s); s = fmaf(qa.w, ta.w, s);
        }
        outrow[t] = f2b(s);
    }
}

// ---------------------------------------------------------------------------
// transpose_v (unchanged)
// ---------------------------------------------------------------------------
__global__ __launch_bounds__(256) void transpose_v(const ushort* __restrict__ vb,
                                                   const float* __restrict__ table_v,
                                                   ushort* __restrict__ vT,
                                                   ushort* __restrict__ tvT) {
    __shared__ ushort tile[128 * 72];
    const int wg  = blockIdx.x;
    const int tid = threadIdx.x;
    if (wg < 512) {
        const int b = wg >> 6, h = (wg >> 2) & 15, kc = wg & 3;
        const int k0 = kc * 128;
        {
            const int kr = tid >> 1, dc = (tid & 1) * 32;
            const ushort* src = vb + ((size_t)(b * SEQ) + k0 + kr) * HID + h * 64 + dc;
#pragma unroll
            for (int j = 0; j < 4; ++j) {
                uint4 u = *(const uint4*)(src + j * 8);
                *(uint4*)&tile[kr * 72 + dc + j * 8] = u;
            }
        }
        __syncthreads();
        {
            const int dr = tid >> 2, kc2 = (tid & 3) * 32;
            ushort* dst = vT + ((size_t)(b * 16 + h) * 64 + dr) * 512 + k0 + kc2;
#pragma unroll
            for (int j = 0; j < 4; ++j) {
                U16x8 o;
#pragma unroll
                for (int i = 0; i < 8; ++i)
                    o.s[i] = tile[(kc2 + j * 8 + i) * 72 + dr];
                *(uint4*)(dst + j * 8) = o.q;
            }
        }
    } else {
        const int tt = tid >> 1, dc = (tid & 1) * 32;
        const float* src = table_v + (size_t)tt * HD + dc;
#pragma unroll
        for (int i = 0; i < 32; ++i)
            tvT[(size_t)(dc + i) * 128 + tt] = f2b(src[i]);
    }
}

// ---------------------------------------------------------------------------
// Fused attention v8 (template ablation):
// MODE bits: 1=GATHER (qtb LDS read), 2=BINS (ds_add_u32 fixed-point),
//            4=GLOBAL (real K/V/fm loads), 8=COMPUTE (MFMA/exp/LDS path).
// REAL = 15. Bins are fixed-point uint (pr * 2^16) -> native ds_add_u32,
// no CAS loop possible.
// ---------------------------------------------------------------------------
template <int MODE>
__global__ __launch_bounds__(256, 3) void attn_mfma(const ushort* __restrict__ qp,
                                                    const ushort* __restrict__ kp,
                                                    const ushort* __restrict__ vT,
                                                    const ushort* __restrict__ qt,
                                                    const int* __restrict__ fmat,
                                                    const float* __restrict__ table_v,
                                                    const ushort* __restrict__ tvT,
                                                    ushort* __restrict__ x) {
    constexpr bool DO_GATHER  = (MODE & 1) != 0;
    constexpr bool DO_BINS    = (MODE & 2) != 0;
    constexpr bool DO_GLOBAL  = (MODE & 4) != 0;
    constexpr bool DO_COMPUTE = (MODE & 8) != 0;
    constexpr float INV_FIX = 1.0f / 65536.0f;

    __shared__ __align__(16) ushort qtb[16 * QSTR];    //  4,352 B
    __shared__ __align__(16) uint   sbin[16 * 132];    //  8,448 B (fixed-point)
    __shared__ __align__(16) ushort P[4][16 * 136];    // 17,408 B (later: obuf f32)
    __shared__ float rowsumw[4][16];                   //    256 B

    const int tid = threadIdx.x;
    const int w   = tid >> 6;         // wave 0..3 -> k-tiles {2w, 2w+1}
    const int l   = tid & 63;
    const int lr  = l & 15;
    const int lg  = l >> 4;

    const int wg   = blockIdx.x;
    const int work = (wg & 7) * 512 + (wg >> 3);
    const int qblk = work & 31;
    const int h    = (work >> 5) & 15;
    const int b    = work >> 9;
    const int q0   = qblk * 16;
    const size_t bSEQ = (size_t)b * SEQ;
    const int hHD = h * HD;

    const int*    fmrow    = fmat + (bSEQ + q0 + lr) * SEQ;
    const ushort* kfr_base = kp + (bSEQ + lr) * HID + hHD;
    const ushort* vfr_base = vT + ((size_t)(b * HEADS + h) * HD + lr) * SEQ;

    bf16x8 qfrag[2];
    {
        const ushort* qrow = qp + (bSEQ + q0 + lr) * HID + hHD;
        qfrag[0] = *(const bf16x8*)(qrow + lg * 8);
        qfrag[1] = *(const bf16x8*)(qrow + 32 + lg * 8);
    }

    // ---- prologue: stage qtab rows, zero bins ----
    {
        const uint4* src = (const uint4*)(qt + ((size_t)(b * HEADS + h) * SEQ + q0) * QSTR);
        uint4* dst = (uint4*)qtb;
        for (int i = tid; i < 16 * QSTR / 8; i += 256) dst[i] = src[i];
    }
    {
        uint4 z = {0u, 0u, 0u, 0u};
        uint4* dz = (uint4*)sbin;
        for (int i = tid; i < 16 * 132 / 4; i += 256) dz[i] = z;
    }
    LDS_BARRIER();                                     // sync1

    if constexpr (!DO_COMPUTE) {
        // MEMONLY: perform all global loads, sink results, no compute/LDS use.
        sink8(qfrag[0]); sink8(qfrag[1]);
#pragma unroll
        for (int t = 0; t < 2; ++t) {
            const int k0 = (w * 2 + t) * 64;
#pragma unroll
            for (int mt = 0; mt < 4; ++mt) {
                sink4i(*(const int4*)&fmrow[k0 + mt * 16 + lg * 4]);
                const ushort* kr = kfr_base + (size_t)(k0 + mt * 16) * HID;
                sink8(*(const bf16x8*)(kr + lg * 8));
                sink8(*(const bf16x8*)(kr + 32 + lg * 8));
            }
#pragma unroll
            for (int nt = 0; nt < 4; ++nt) {
                const ushort* vr = vfr_base + (size_t)nt * 16 * SEQ + k0;
                sink8(*(const bf16x8*)(vr + lg * 8));
                sink8(*(const bf16x8*)(vr + 32 + lg * 8));
            }
        }
        return;
    }

    // ---- Phase 1: QK^T + gather + exp + bins + P ----
    float lsum = 0.f;
#pragma unroll
    for (int t = 0; t < 2; ++t) {
        const int k0 = (w * 2 + t) * 64;
#pragma unroll
        for (int mt = 0; mt < 4; ++mt) {
            bf16x8 ka0, ka1;
            int4 fm4;
            if constexpr (DO_GLOBAL) {
                const ushort* kr = kfr_base + (size_t)(k0 + mt * 16) * HID;
                ka0 = *(const bf16x8*)(kr + lg * 8);
                ka1 = *(const bf16x8*)(kr + 32 + lg * 8);
                fm4 = *(const int4*)&fmrow[k0 + mt * 16 + lg * 4];
            } else {
                ka0 = qfrag[0]; ka1 = qfrag[1];   // synthetic operands (NOKV)
                fm4.x = (lr * 5 + mt * 13 + lg) & 127;
                fm4.y = (lr * 7 + mt * 11 + lg * 3 + 1) & 127;
                fm4.z = (lr * 3 + mt * 17 + lg * 5 + 2) & 127;
                fm4.w = (lr * 9 + mt * 19 + lg * 7 + 3) & 127;
            }
            f32x4 st = (f32x4){0.f, 0.f, 0.f, 0.f};
            st = __builtin_amdgcn_mfma_f32_16x16x32_bf16(ka0, qfrag[0], st, 0, 0, 0);
            st = __builtin_amdgcn_mfma_f32_16x16x32_bf16(ka1, qfrag[1], st, 0, 0, 0);
            float g0 = 0.f, g1 = 0.f, g2 = 0.f, g3 = 0.f;
            if constexpr (DO_GATHER) {
                g0 = b2f(qtb[lr * QSTR + fm4.x]);
                g1 = b2f(qtb[lr * QSTR + fm4.y]);
                g2 = b2f(qtb[lr * QSTR + fm4.z]);
                g3 = b2f(qtb[lr * QSTR + fm4.w]);
            } else {
                sink4i(fm4);   // keep fm load alive when gather is ablated
            }
            float pr0 = __expf((st[0] + g0) * 0.125f);
            float pr1 = __expf((st[1] + g1) * 0.125f);
            float pr2 = __expf((st[2] + g2) * 0.125f);
            float pr3 = __expf((st[3] + g3) * 0.125f);
            lsum += pr0 + pr1 + pr2 + pr3;
            if constexpr (DO_BINS) {
                __hip_atomic_fetch_add(&sbin[lr * 132 + fm4.x], (uint)(pr0 * 65536.f),
                                       __ATOMIC_RELAXED, __HIP_MEMORY_SCOPE_WORKGROUP);
                __hip_atomic_fetch_add(&sbin[lr * 132 + fm4.y], (uint)(pr1 * 65536.f),
                                       __ATOMIC_RELAXED, __HIP_MEMORY_SCOPE_WORKGROUP);
                __hip_atomic_fetch_add(&sbin[lr * 132 + fm4.z], (uint)(pr2 * 65536.f),
                                       __ATOMIC_RELAXED, __HIP_MEMORY_SCOPE_WORKGROUP);
                __hip_atomic_fetch_add(&sbin[lr * 132 + fm4.w], (uint)(pr3 * 65536.f),
                                       __ATOMIC_RELAXED, __HIP_MEMORY_SCOPE_WORKGROUP);
            }
            uint2 pu;
            pu.x = pk(pr0, pr1); pu.y = pk(pr2, pr3);
            *(uint2*)&P[w][lr * 136 + t * 64 + mt * 16 + lg * 4] = pu;
        }
    }
    lsum += __shfl_xor(lsum, 16);
    lsum += __shfl_xor(lsum, 32);
    if (lg == 0) rowsumw[w][lr] = lsum;

    // ---- PV (own-wave P; V from global or synthetic) ----
    f32x4 acc_o[4];
#pragma unroll
    for (int nt = 0; nt < 4; ++nt) acc_o[nt] = (f32x4){0.f, 0.f, 0.f, 0.f};
#pragma unroll
    for (int t = 0; t < 2; ++t) {
        const int k0 = (w * 2 + t) * 64;
        bf16x8 pa0 = *(const bf16x8*)&P[w][lr * 136 + t * 64 + lg * 8];
        bf16x8 pa1 = *(const bf16x8*)&P[w][lr * 136 + t * 64 + 32 + lg * 8];
#pragma unroll
        for (int nt = 0; nt < 4; ++nt) {
            bf16x8 vb0, vb1;
            if constexpr (DO_GLOBAL) {
                const ushort* vr = vfr_base + (size_t)nt * 16 * SEQ + k0;
                vb0 = *(const bf16x8*)(vr + lg * 8);
                vb1 = *(const bf16x8*)(vr + 32 + lg * 8);
            } else {
                vb0 = qfrag[0]; vb1 = qfrag[1];
            }
            acc_o[nt] = __builtin_amdgcn_mfma_f32_16x16x32_bf16(pa0, vb0, acc_o[nt], 0, 0, 0);
            acc_o[nt] = __builtin_amdgcn_mfma_f32_16x16x32_bf16(pa1, vb1, acc_o[nt], 0, 0, 0);
        }
    }

    LDS_BARRIER();                                     // sync2: bins done, P dead

    // ---- w2 slice: t-range [w*32, w*32+32) (fixed-point bins -> float) ----
    {
        const uint* sp = &sbin[lr * 132 + w * 32 + lg * 8];
        bf16x8 af = pack8((float)sp[0] * INV_FIX, (float)sp[1] * INV_FIX,
                          (float)sp[2] * INV_FIX, (float)sp[3] * INV_FIX,
                          (float)sp[4] * INV_FIX, (float)sp[5] * INV_FIX,
                          (float)sp[6] * INV_FIX, (float)sp[7] * INV_FIX);
#pragma unroll
        for (int nt = 0; nt < 4; ++nt) {
            bf16x8 bf_ = *(const bf16x8*)(tvT + (size_t)(nt * 16 + lr) * 128 + w * 32 + lg * 8);
            acc_o[nt] = __builtin_amdgcn_mfma_f32_16x16x32_bf16(af, bf_, acc_o[nt], 0, 0, 0);
        }
    }

    // ---- cross-wave O reduction through dead P region ----
    float* obuf = (float*)&P[0][0];
    if (w != 0) {
#pragma unroll
        for (int nt = 0; nt < 4; ++nt)
            *(f32x4*)&obuf[(((w - 1) * 4 + nt) * 64 + l) * 4] = acc_o[nt];
    }
    LDS_BARRIER();                                     // sync3

    if (w == 0) {
#pragma unroll
        for (int j = 0; j < 3; ++j)
#pragma unroll
            for (int nt = 0; nt < 4; ++nt) {
                f32x4 p_ = *(const f32x4*)&obuf[((j * 4 + nt) * 64 + l) * 4];
                acc_o[nt][0] += p_[0]; acc_o[nt][1] += p_[1];
                acc_o[nt][2] += p_[2]; acc_o[nt][3] += p_[3];
            }
        float iv[4], nb[4];
#pragma unroll
        for (int r = 0; r < 4; ++r) {
            const int q = lg * 4 + r;
            iv[r] = 1.f / (rowsumw[0][q] + rowsumw[1][q] + rowsumw[2][q] + rowsumw[3][q]);
            nb[r] = (float)sbin[q * 132 + 128] * INV_FIX;   // t=128 tail bin
        }
        ushort* orow = x + (bSEQ + q0 + lg * 4) * HID + hHD;
#pragma unroll
        for (int nt = 0; nt < 4; ++nt) {
            float tv = table_v[(size_t)128 * HD + nt * 16 + lr];
#pragma unroll
            for (int r = 0; r < 4; ++r) {
                float o = (acc_o[nt][r] + nb[r] * tv) * iv[r];
                orow[(size_t)r * HID + nt * 16 + lr] = f2b(o);
            }
        }
    }
}

// ---------------------------------------------------------------------------
extern "C" void kernel_launch(void* const* d_in, const int* in_sizes, int n_in,
                              void* d_out, int out_size, void* d_ws, size_t ws_size,
                              hipStream_t stream) {
    const float* query = (const float*)d_in[0];
    const float* key   = (const float*)d_in[1];
    const float* value = (const float*)d_in[2];
    const int*   fmat  = (const int*)d_in[3];
    const float* Wq = (const float*)d_in[4];
    const float* bq = (const float*)d_in[5];
    const float* Wk = (const float*)d_in[6];
    const float* bk = (const float*)d_in[7];
    const float* Wv = (const float*)d_in[8];
    const float* bv = (const float*)d_in[9];
    const float* Wo = (const float*)d_in[10];
    const float* bo = (const float*)d_in[11];
    const float* table_k = (const float*)d_in[12];
    const float* table_v = (const float*)d_in[13];

    const size_t nBLD = (size_t)BATCH * SEQ * HID;   // 4,194,304
    const size_t nW   = (size_t)HID * HID;           // 1,048,576
    ushort* us = (ushort*)d_ws;
    ushort* qin16 = us;                 us += nBLD;   // later reused as vT
    ushort* kin16 = us;                 us += nBLD;   // later reused as tvT
    ushort* vin16 = us;                 us += nBLD;
    ushort* wq16  = us;                 us += nW;
    ushort* wk16  = us;                 us += nW;
    ushort* wv16  = us;                 us += nW;
    ushort* wo16  = us;                 us += nW;
    ushort* qb16  = us;                 us += nBLD;
    ushort* kb16  = us;                 us += nBLD;
    ushort* vb16  = us;                 us += nBLD;
    ushort* qt16  = us;                 us += (size_t)BATCH * HEADS * SEQ * QSTR;
    ushort* xb16  = us;                 us += nBLD;

    ConvArgs ca;
    ca.src[0] = query; ca.src[1] = key; ca.src[2] = value;
    ca.src[3] = Wq; ca.src[4] = Wk; ca.src[5] = Wv; ca.src[6] = Wo;
    ca.dst[0] = qin16; ca.dst[1] = kin16; ca.dst[2] = vin16;
    ca.dst[3] = wq16; ca.dst[4] = wk16; ca.dst[5] = wv16; ca.dst[6] = wo16;
    convert_bf16<<<dim3(8192), 256, 0, stream>>>(ca);

    const int M = BATCH * SEQ;  // 4096

    GemmArgs gq = {};
    gq.A[0] = qin16; gq.A[1] = kin16; gq.A[2] = vin16;
    gq.W[0] = wq16;  gq.W[1] = wk16;  gq.W[2] = wv16;
    gq.bias[0] = bq; gq.bias[1] = bk; gq.bias[2] = bv;
    gq.Cf[0] = nullptr; gq.Cf[1] = nullptr; gq.Cf[2] = nullptr;
    gq.Cb[0] = qb16; gq.Cb[1] = kb16; gq.Cb[2] = vb16;
    gemm_bf16<<<dim3(HID / 128, M / 128, 3), 256, 0, stream>>>(gq, M, HID, HID);

    qtab_kernel<<<dim3(SEQ/64, HEADS, BATCH), 256, 0, stream>>>(qb16, table_k, qt16);

    ushort* vTbuf  = qin16;   // [B,H,64,512] bf16
    ushort* tvTbuf = kin16;   // [64,128] bf16
    transpose_v<<<dim3(513), 256, 0, stream>>>(vb16, table_v, vTbuf, tvTbuf);

    const dim3 agrid(BATCH * HEADS * (SEQ/16));
    // ---- ablation dispatches (write only xb16; real attn overwrites it) ----
    attn_mfma<13><<<agrid, 256, 0, stream>>>(   // NOBINS  (gather+global+compute)
        qb16, kb16, vTbuf, qt16, fmat, table_v, tvTbuf, xb16);
    attn_mfma<14><<<agrid, 256, 0, stream>>>(   // NOGATHER (bins+global+compute)
        qb16, kb16, vTbuf, qt16, fmat, table_v, tvTbuf, xb16);
    attn_mfma<4><<<agrid, 256, 0, stream>>>(    // MEMONLY  (global loads only)
        qb16, kb16, vTbuf, qt16, fmat, table_v, tvTbuf, xb16);
    attn_mfma<11><<<agrid, 256, 0, stream>>>(   // NOKV     (compute, no global K/V/fm)
        qb16, kb16, vTbuf, qt16, fmat, table_v, tvTbuf, xb16);

    // ---- real attention (fixed-point ds_add_u32 bins) ----
    attn_mfma<15><<<agrid, 256, 0, stream>>>(
        qb16, kb16, vTbuf, qt16, fmat, table_v, tvTbuf, xb16);

    GemmArgs go = {};
    go.A[0] = xb16; go.W[0] = wo16; go.bias[0] = bo;
    go.Cf[0] = (float*)d_out; go.Cb[0] = nullptr;
    gemm_bf16<<<dim3(HID / 128, M / 128, 1), 256, 0, stream>>>(go, M, HID, HID);
}

// Round 10
// 229.793 us; speedup vs baseline: 2.1683x; 2.1683x over previous
//
#include <hip/hip_runtime.h>

#define HID 1024
#define HEADS 16
#define HD 64
#define TAB 129
#define QSTR 136   // padded qtab row stride (ushorts, 16B-aligned rows)
#define BATCH 8
#define SEQ 512

typedef unsigned int uint;
typedef unsigned short ushort;
typedef __attribute__((ext_vector_type(4))) float f32x4;
typedef __attribute__((ext_vector_type(8))) __bf16 bf16x8;

// ---------------------------------------------------------------------------
// bf16 helpers
// ---------------------------------------------------------------------------
__device__ __forceinline__ ushort f2b(float x) {
    uint b = __float_as_uint(x);
    uint r = (b + 0x7fffu + ((b >> 16) & 1u)) >> 16;
    return (ushort)r;
}
__device__ __forceinline__ uint pk(float lo, float hi) {
    return (uint)f2b(lo) | ((uint)f2b(hi) << 16);
}
__device__ __forceinline__ float b2f(ushort u) {
    return __uint_as_float(((uint)u) << 16);
}
__device__ __forceinline__ void unpack8(uint4 u, float* f) {
    f[0] = __uint_as_float(u.x << 16); f[1] = __uint_as_float(u.x & 0xffff0000u);
    f[2] = __uint_as_float(u.y << 16); f[3] = __uint_as_float(u.y & 0xffff0000u);
    f[4] = __uint_as_float(u.z << 16); f[5] = __uint_as_float(u.z & 0xffff0000u);
    f[6] = __uint_as_float(u.w << 16); f[7] = __uint_as_float(u.w & 0xffff0000u);
}
union U16x8 { uint u[4]; bf16x8 v; ushort s[8]; uint4 q; };
__device__ __forceinline__ bf16x8 pack8(float a0, float a1, float a2, float a3,
                                        float a4, float a5, float a6, float a7) {
    U16x8 r;
    r.u[0] = pk(a0, a1); r.u[1] = pk(a2, a3);
    r.u[2] = pk(a4, a5); r.u[3] = pk(a6, a7);
    return r.v;
}

#define GL16(gp, lp) __builtin_amdgcn_global_load_lds( \
    (const __attribute__((address_space(1))) void*)(gp), \
    (__attribute__((address_space(3))) void*)(lp), 16, 0, 0)

// LDS-only barrier: order DS ops, keep in-flight VMEM alive
#define LDS_BARRIER() do { \
        asm volatile("s_waitcnt lgkmcnt(0)" ::: "memory"); \
        __builtin_amdgcn_s_barrier(); \
    } while (0)

// ---------------------------------------------------------------------------
// convert fp32 -> bf16
// ---------------------------------------------------------------------------
struct ConvArgs { const float* src[7]; ushort* dst[7]; };

__global__ __launch_bounds__(256) void convert_bf16(ConvArgs ca) {
    int bid = blockIdx.x;
    int ti, lb;
    if (bid < 6144) { ti = bid >> 11; lb = bid & 2047; }
    else { int r = bid - 6144; ti = 3 + (r >> 9); lb = r & 511; }
    const float* s = ca.src[ti] + (size_t)lb * 2048 + (threadIdx.x << 3);
    ushort*      d = ca.dst[ti] + (size_t)lb * 2048 + (threadIdx.x << 3);
    float4 a = *(const float4*)s;
    float4 c = *(const float4*)(s + 4);
    uint4 u;
    u.x = pk(a.x, a.y); u.y = pk(a.z, a.w);
    u.z = pk(c.x, c.y); u.w = pk(c.z, c.w);
    *(uint4*)d = u;
}

// ---------------------------------------------------------------------------
// bf16 MFMA GEMM (unchanged): C_z = A_z @ W_z^T + bias_z
// ---------------------------------------------------------------------------
struct GemmArgs {
    const ushort* A[3];
    const ushort* W[3];
    const float*  bias[3];
    float*        Cf[3];
    ushort*       Cb[3];
};

__global__ __launch_bounds__(256) void gemm_bf16(GemmArgs ga, int M, int N, int K) {
    __shared__ ushort As[2][128 * 32];
    __shared__ ushort Bs[2][128 * 32];
    const int z = blockIdx.z;
    const ushort* A = ga.A[z];
    const ushort* W = ga.W[z];
    const int tid = threadIdx.x;
    const int m0 = blockIdx.y * 128;
    const int n0 = blockIdx.x * 128;

    const int w  = tid >> 6;
    const int l  = tid & 63;
    const int lr = l & 15;
    const int lg = l >> 4;
    const int wm = w >> 1;
    const int wn = w & 1;

    const int sr = tid >> 2;
    const int sc = tid & 3;
    const int g  = sc ^ ((sr >> 1) & 3);
    const ushort* Ag0 = A + (size_t)(m0 + sr)      * K + g * 8;
    const ushort* Ag1 = A + (size_t)(m0 + sr + 64) * K + g * 8;
    const ushort* Wg0 = W + (size_t)(n0 + sr)      * K + g * 8;
    const ushort* Wg1 = W + (size_t)(n0 + sr + 64) * K + g * 8;

    f32x4 acc[4][4];
#pragma unroll
    for (int mt = 0; mt < 4; ++mt)
#pragma unroll
        for (int nt = 0; nt < 4; ++nt) acc[mt][nt] = (f32x4){0.f, 0.f, 0.f, 0.f};

#define STAGE(buf, k0) do { \
        GL16(Ag0 + (k0), &As[buf][w * 512]); \
        GL16(Ag1 + (k0), &As[buf][2048 + w * 512]); \
        GL16(Wg0 + (k0), &Bs[buf][w * 512]); \
        GL16(Wg1 + (k0), &Bs[buf][2048 + w * 512]); \
    } while (0)

    const int swz = (lr >> 1) & 3;
#define COMPUTE(buf) do { \
        bf16x8 af[4], bf[4]; \
        _Pragma("unroll") \
        for (int mt = 0; mt < 4; ++mt) \
            af[mt] = *(const bf16x8*)&As[buf][(wm * 64 + mt * 16 + lr) * 32 + (lg ^ swz) * 8]; \
        _Pragma("unroll") \
        for (int nt = 0; nt < 4; ++nt) \
            bf[nt] = *(const bf16x8*)&Bs[buf][(wn * 64 + nt * 16 + lr) * 32 + (lg ^ swz) * 8]; \
        _Pragma("unroll") \
        for (int mt = 0; mt < 4; ++mt) \
            _Pragma("unroll") \
            for (int nt = 0; nt < 4; ++nt) \
                acc[mt][nt] = __builtin_amdgcn_mfma_f32_16x16x32_bf16(af[mt], bf[nt], acc[mt][nt], 0, 0, 0); \
    } while (0)

    STAGE(0, 0);
    __syncthreads();
    const int nk = K / 32;
    for (int t = 0; t < nk - 1; ++t) {
        STAGE((t + 1) & 1, (size_t)(t + 1) * 32);
        COMPUTE(t & 1);
        __syncthreads();
    }
    COMPUTE((nk - 1) & 1);

    const float* bias = ga.bias[z];
    float bv[4];
#pragma unroll
    for (int nt = 0; nt < 4; ++nt) bv[nt] = bias[n0 + wn * 64 + nt * 16 + lr];
    float*  Cf = ga.Cf[z];
    ushort* Cb = ga.Cb[z];
    if (Cf) {
#pragma unroll
        for (int mt = 0; mt < 4; ++mt)
#pragma unroll
            for (int r4 = 0; r4 < 4; ++r4) {
                size_t m = m0 + wm * 64 + mt * 16 + lg * 4 + r4;
                float* crow = Cf + m * N + n0 + wn * 64 + lr;
#pragma unroll
                for (int nt = 0; nt < 4; ++nt)
                    crow[nt * 16] = acc[mt][nt][r4] + bv[nt];
            }
    } else {
#pragma unroll
        for (int mt = 0; mt < 4; ++mt)
#pragma unroll
            for (int r4 = 0; r4 < 4; ++r4) {
                size_t m = m0 + wm * 64 + mt * 16 + lg * 4 + r4;
                ushort* crow = Cb + m * N + n0 + wn * 64 + lr;
#pragma unroll
                for (int nt = 0; nt < 4; ++nt)
                    crow[nt * 16] = f2b(acc[mt][nt][r4] + bv[nt]);
            }
    }
#undef STAGE
#undef COMPUTE
}

// ---------------------------------------------------------------------------
// qtab kernel (unchanged)
// ---------------------------------------------------------------------------
__global__ __launch_bounds__(256) void qtab_kernel(const ushort* __restrict__ q4,
                                                   const float* __restrict__ table_k,
                                                   ushort* __restrict__ qtab) {
    __shared__ float qs[64][68];
    __shared__ float tk[TAB][68];
    const int tid = threadIdx.x;
    const int q0 = blockIdx.x * 64;
    const int h  = blockIdx.y;
    const int b  = blockIdx.z;
    for (int f = tid; f < 512; f += 256) {
        int r  = f >> 3;
        int dd = (f & 7) << 3;
        uint4 u = *(const uint4*)&q4[((size_t)(b*SEQ + q0 + r)) * HID + h*HD + dd];
        float f8[8];
        unpack8(u, f8);
#pragma unroll
        for (int j = 0; j < 8; ++j) qs[r][dd + j] = f8[j];
    }
    for (int f = tid; f < TAB*16; f += 256) {
        int t  = f >> 4;
        int dd = (f & 15) << 2;
        *(float4*)&tk[t][dd] = *(const float4*)&table_k[t*HD + dd];
    }
    __syncthreads();
    const int tq = tid >> 2;
    const int tg = tid & 3;
    ushort* outrow = qtab + ((size_t)(b*HEADS + h) * SEQ + q0 + tq) * QSTR;
    for (int t = tg; t < TAB; t += 4) {
        float s = 0.f;
#pragma unroll
        for (int d = 0; d < HD; d += 4) {
            float4 qa = *(const float4*)&qs[tq][d];
            float4 ta = *(const float4*)&tk[t][d];
            s = fmaf(qa.x, ta.x, s); s = fmaf(qa.y, ta.y, s);
            s = fmaf(qa.z, ta.z, s); s = fmaf(qa.w, ta.w, s);
        }
        outrow[t] = f2b(s);
    }
}

// ---------------------------------------------------------------------------
// transpose_v (unchanged)
// ---------------------------------------------------------------------------
__global__ __launch_bounds__(256) void transpose_v(const ushort* __restrict__ vb,
                                                   const float* __restrict__ table_v,
                                                   ushort* __restrict__ vT,
                                                   ushort* __restrict__ tvT) {
    __shared__ ushort tile[128 * 72];
    const int wg  = blockIdx.x;
    const int tid = threadIdx.x;
    if (wg < 512) {
        const int b = wg >> 6, h = (wg >> 2) & 15, kc = wg & 3;
        const int k0 = kc * 128;
        {
            const int kr = tid >> 1, dc = (tid & 1) * 32;
            const ushort* src = vb + ((size_t)(b * SEQ) + k0 + kr) * HID + h * 64 + dc;
#pragma unroll
            for (int j = 0; j < 4; ++j) {
                uint4 u = *(const uint4*)(src + j * 8);
                *(uint4*)&tile[kr * 72 + dc + j * 8] = u;
            }
        }
        __syncthreads();
        {
            const int dr = tid >> 2, kc2 = (tid & 3) * 32;
            ushort* dst = vT + ((size_t)(b * 16 + h) * 64 + dr) * 512 + k0 + kc2;
#pragma unroll
            for (int j = 0; j < 4; ++j) {
                U16x8 o;
#pragma unroll
                for (int i = 0; i < 8; ++i)
                    o.s[i] = tile[(kc2 + j * 8 + i) * 72 + dr];
                *(uint4*)(dst + j * 8) = o.q;
            }
        }
    } else {
        const int tt = tid >> 1, dc = (tid & 1) * 32;
        const float* src = table_v + (size_t)tt * HD + dc;
#pragma unroll
        for (int i = 0; i < 32; ++i)
            tvT[(size_t)(dc + i) * 128 + tt] = f2b(src[i]);
    }
}

// ---------------------------------------------------------------------------
// Fused attention v9: k-split 4 waves x 2 k-tiles; fixed-point ds_add_u32
// bins (R9-verified); phase 1 split into a pure {load+MFMA} pass (pass A,
// no LDS ops -> compiler pipelines the 16 K-loads) then the softmax pass.
// ---------------------------------------------------------------------------
__global__ __launch_bounds__(256, 3) void attn_mfma(const ushort* __restrict__ qp,
                                                    const ushort* __restrict__ kp,
                                                    const ushort* __restrict__ vT,
                                                    const ushort* __restrict__ qt,
                                                    const int* __restrict__ fmat,
                                                    const float* __restrict__ table_v,
                                                    const ushort* __restrict__ tvT,
                                                    ushort* __restrict__ x) {
    constexpr float FIX = 65536.0f;
    constexpr float INV_FIX = 1.0f / 65536.0f;

    __shared__ __align__(16) ushort qtb[16 * QSTR];    //  4,352 B
    __shared__ __align__(16) uint   sbin[16 * 132];    //  8,448 B (fixed-point)
    __shared__ __align__(16) ushort P[4][16 * 136];    // 17,408 B (later: obuf f32)
    __shared__ float rowsumw[4][16];                   //    256 B

    const int tid = threadIdx.x;
    const int w   = tid >> 6;         // wave 0..3 -> k-tiles {2w, 2w+1}
    const int l   = tid & 63;
    const int lr  = l & 15;
    const int lg  = l >> 4;

    const int wg   = blockIdx.x;
    const int work = (wg & 7) * 512 + (wg >> 3);
    const int qblk = work & 31;
    const int h    = (work >> 5) & 15;
    const int b    = work >> 9;
    const int q0   = qblk * 16;
    const size_t bSEQ = (size_t)b * SEQ;
    const int hHD = h * HD;

    const int*    fmrow    = fmat + (bSEQ + q0 + lr) * SEQ;
    const ushort* kfr_base = kp + (bSEQ + lr) * HID + hHD;
    const ushort* vfr_base = vT + ((size_t)(b * HEADS + h) * HD + lr) * SEQ;

    bf16x8 qfrag[2];
    {
        const ushort* qrow = qp + (bSEQ + q0 + lr) * HID + hHD;
        qfrag[0] = *(const bf16x8*)(qrow + lg * 8);
        qfrag[1] = *(const bf16x8*)(qrow + 32 + lg * 8);
    }

    // ---- prologue: stage qtab rows, zero bins ----
    {
        const uint4* src = (const uint4*)(qt + ((size_t)(b * HEADS + h) * SEQ + q0) * QSTR);
        uint4* dst = (uint4*)qtb;
        for (int i = tid; i < 16 * QSTR / 8; i += 256) dst[i] = src[i];
    }
    {
        uint4 z = {0u, 0u, 0u, 0u};
        uint4* dz = (uint4*)sbin;
        for (int i = tid; i < 16 * 132 / 4; i += 256) dz[i] = z;
    }
    LDS_BARRIER();                                     // sync1

    // ---- Phase 1a: pure {K/fm load + MFMA} stream (pipelinable) ----
    f32x4 stv[8];
    int4  fmr[8];
#pragma unroll
    for (int i = 0; i < 8; ++i) {
        const int t  = i >> 2;
        const int mt = i & 3;
        const int k0 = (w * 2 + t) * 64;
        const ushort* kr = kfr_base + (size_t)(k0 + mt * 16) * HID;
        bf16x8 ka0 = *(const bf16x8*)(kr + lg * 8);
        bf16x8 ka1 = *(const bf16x8*)(kr + 32 + lg * 8);
        fmr[i] = *(const int4*)&fmrow[k0 + mt * 16 + lg * 4];
        f32x4 st = (f32x4){0.f, 0.f, 0.f, 0.f};
        st = __builtin_amdgcn_mfma_f32_16x16x32_bf16(ka0, qfrag[0], st, 0, 0, 0);
        st = __builtin_amdgcn_mfma_f32_16x16x32_bf16(ka1, qfrag[1], st, 0, 0, 0);
        stv[i] = st;
    }

    // ---- Phase 1b: gather + exp + bins (u32 fixed-point) + P ----
    float lsum = 0.f;
#pragma unroll
    for (int i = 0; i < 8; ++i) {
        const int t  = i >> 2;
        const int mt = i & 3;
        const int4 fm4 = fmr[i];
        const f32x4 st = stv[i];
        float pr0 = __expf((st[0] + b2f(qtb[lr * QSTR + fm4.x])) * 0.125f);
        float pr1 = __expf((st[1] + b2f(qtb[lr * QSTR + fm4.y])) * 0.125f);
        float pr2 = __expf((st[2] + b2f(qtb[lr * QSTR + fm4.z])) * 0.125f);
        float pr3 = __expf((st[3] + b2f(qtb[lr * QSTR + fm4.w])) * 0.125f);
        lsum += pr0 + pr1 + pr2 + pr3;
        __hip_atomic_fetch_add(&sbin[lr * 132 + fm4.x], (uint)(pr0 * FIX),
                               __ATOMIC_RELAXED, __HIP_MEMORY_SCOPE_WORKGROUP);
        __hip_atomic_fetch_add(&sbin[lr * 132 + fm4.y], (uint)(pr1 * FIX),
                               __ATOMIC_RELAXED, __HIP_MEMORY_SCOPE_WORKGROUP);
        __hip_atomic_fetch_add(&sbin[lr * 132 + fm4.z], (uint)(pr2 * FIX),
                               __ATOMIC_RELAXED, __HIP_MEMORY_SCOPE_WORKGROUP);
        __hip_atomic_fetch_add(&sbin[lr * 132 + fm4.w], (uint)(pr3 * FIX),
                               __ATOMIC_RELAXED, __HIP_MEMORY_SCOPE_WORKGROUP);
        uint2 pu;
        pu.x = pk(pr0, pr1); pu.y = pk(pr2, pr3);
        *(uint2*)&P[w][lr * 136 + t * 64 + mt * 16 + lg * 4] = pu;
    }
    lsum += __shfl_xor(lsum, 16);
    lsum += __shfl_xor(lsum, 32);
    if (lg == 0) rowsumw[w][lr] = lsum;

    // ---- PV (own-wave P; V-frag loads pipeline across MFMAs) ----
    f32x4 acc_o[4];
#pragma unroll
    for (int nt = 0; nt < 4; ++nt) acc_o[nt] = (f32x4){0.f, 0.f, 0.f, 0.f};
#pragma unroll
    for (int t = 0; t < 2; ++t) {
        const int k0 = (w * 2 + t) * 64;
        bf16x8 pa0 = *(const bf16x8*)&P[w][lr * 136 + t * 64 + lg * 8];
        bf16x8 pa1 = *(const bf16x8*)&P[w][lr * 136 + t * 64 + 32 + lg * 8];
#pragma unroll
        for (int nt = 0; nt < 4; ++nt) {
            const ushort* vr = vfr_base + (size_t)nt * 16 * SEQ + k0;
            bf16x8 vb0 = *(const bf16x8*)(vr + lg * 8);
            bf16x8 vb1 = *(const bf16x8*)(vr + 32 + lg * 8);
            acc_o[nt] = __builtin_amdgcn_mfma_f32_16x16x32_bf16(pa0, vb0, acc_o[nt], 0, 0, 0);
            acc_o[nt] = __builtin_amdgcn_mfma_f32_16x16x32_bf16(pa1, vb1, acc_o[nt], 0, 0, 0);
        }
    }

    LDS_BARRIER();                                     // sync2: bins done, P dead

    // ---- w2 slice: t-range [w*32, w*32+32) (fixed-point bins -> float) ----
    {
        const uint* sp = &sbin[lr * 132 + w * 32 + lg * 8];
        bf16x8 af = pack8((float)sp[0] * INV_FIX, (float)sp[1] * INV_FIX,
                          (float)sp[2] * INV_FIX, (float)sp[3] * INV_FIX,
                          (float)sp[4] * INV_FIX, (float)sp[5] * INV_FIX,
                          (float)sp[6] * INV_FIX, (float)sp[7] * INV_FIX);
#pragma unroll
        for (int nt = 0; nt < 4; ++nt) {
            bf16x8 bf_ = *(const bf16x8*)(tvT + (size_t)(nt * 16 + lr) * 128 + w * 32 + lg * 8);
            acc_o[nt] = __builtin_amdgcn_mfma_f32_16x16x32_bf16(af, bf_, acc_o[nt], 0, 0, 0);
        }
    }

    // ---- cross-wave O reduction through dead P region ----
    float* obuf = (float*)&P[0][0];
    if (w != 0) {
#pragma unroll
        for (int nt = 0; nt < 4; ++nt)
            *(f32x4*)&obuf[(((w - 1) * 4 + nt) * 64 + l) * 4] = acc_o[nt];
    }
    LDS_BARRIER();                                     // sync3

    if (w == 0) {
#pragma unroll
        for (int j = 0; j < 3; ++j)
#pragma unroll
            for (int nt = 0; nt < 4; ++nt) {
                f32x4 p_ = *(const f32x4*)&obuf[((j * 4 + nt) * 64 + l) * 4];
                acc_o[nt][0] += p_[0]; acc_o[nt][1] += p_[1];
                acc_o[nt][2] += p_[2]; acc_o[nt][3] += p_[3];
            }
        float iv[4], nb[4];
#pragma unroll
        for (int r = 0; r < 4; ++r) {
            const int q = lg * 4 + r;
            iv[r] = 1.f / (rowsumw[0][q] + rowsumw[1][q] + rowsumw[2][q] + rowsumw[3][q]);
            nb[r] = (float)sbin[q * 132 + 128] * INV_FIX;   // t=128 tail bin
        }
        ushort* orow = x + (bSEQ + q0 + lg * 4) * HID + hHD;
#pragma unroll
        for (int nt = 0; nt < 4; ++nt) {
            float tv = table_v[(size_t)128 * HD + nt * 16 + lr];
#pragma unroll
            for (int r = 0; r < 4; ++r) {
                float o = (acc_o[nt][r] + nb[r] * tv) * iv[r];
                orow[(size_t)r * HID + nt * 16 + lr] = f2b(o);
            }
        }
    }
}

// ---------------------------------------------------------------------------
extern "C" void kernel_launch(void* const* d_in, const int* in_sizes, int n_in,
                              void* d_out, int out_size, void* d_ws, size_t ws_size,
                              hipStream_t stream) {
    const float* query = (const float*)d_in[0];
    const float* key   = (const float*)d_in[1];
    const float* value = (const float*)d_in[2];
    const int*   fmat  = (const int*)d_in[3];
    const float* Wq = (const float*)d_in[4];
    const float* bq = (const float*)d_in[5];
    const float* Wk = (const float*)d_in[6];
    const float* bk = (const float*)d_in[7];
    const float* Wv = (const float*)d_in[8];
    const float* bv = (const float*)d_in[9];
    const float* Wo = (const float*)d_in[10];
    const float* bo = (const float*)d_in[11];
    const float* table_k = (const float*)d_in[12];
    const float* table_v = (const float*)d_in[13];

    const size_t nBLD = (size_t)BATCH * SEQ * HID;   // 4,194,304
    const size_t nW   = (size_t)HID * HID;           // 1,048,576
    ushort* us = (ushort*)d_ws;
    ushort* qin16 = us;                 us += nBLD;   // later reused as vT
    ushort* kin16 = us;                 us += nBLD;   // later reused as tvT
    ushort* vin16 = us;                 us += nBLD;
    ushort* wq16  = us;                 us += nW;
    ushort* wk16  = us;                 us += nW;
    ushort* wv16  = us;                 us += nW;
    ushort* wo16  = us;                 us += nW;
    ushort* qb16  = us;                 us += nBLD;
    ushort* kb16  = us;                 us += nBLD;
    ushort* vb16  = us;                 us += nBLD;
    ushort* qt16  = us;                 us += (size_t)BATCH * HEADS * SEQ * QSTR;
    ushort* xb16  = us;                 us += nBLD;

    ConvArgs ca;
    ca.src[0] = query; ca.src[1] = key; ca.src[2] = value;
    ca.src[3] = Wq; ca.src[4] = Wk; ca.src[5] = Wv; ca.src[6] = Wo;
    ca.dst[0] = qin16; ca.dst[1] = kin16; ca.dst[2] = vin16;
    ca.dst[3] = wq16; ca.dst[4] = wk16; ca.dst[5] = wv16; ca.dst[6] = wo16;
    convert_bf16<<<dim3(8192), 256, 0, stream>>>(ca);

    const int M = BATCH * SEQ;  // 4096

    GemmArgs gq = {};
    gq.A[0] = qin16; gq.A[1] = kin16; gq.A[2] = vin16;
    gq.W[0] = wq16;  gq.W[1] = wk16;  gq.W[2] = wv16;
    gq.bias[0] = bq; gq.bias[1] = bk; gq.bias[2] = bv;
    gq.Cf[0] = nullptr; gq.Cf[1] = nullptr; gq.Cf[2] = nullptr;
    gq.Cb[0] = qb16; gq.Cb[1] = kb16; gq.Cb[2] = vb16;
    gemm_bf16<<<dim3(HID / 128, M / 128, 3), 256, 0, stream>>>(gq, M, HID, HID);

    qtab_kernel<<<dim3(SEQ/64, HEADS, BATCH), 256, 0, stream>>>(qb16, table_k, qt16);

    ushort* vTbuf  = qin16;   // [B,H,64,512] bf16
    ushort* tvTbuf = kin16;   // [64,128] bf16
    transpose_v<<<dim3(513), 256, 0, stream>>>(vb16, table_v, vTbuf, tvTbuf);

    attn_mfma<<<dim3(BATCH * HEADS * (SEQ/16)), 256, 0, stream>>>(
        qb16, kb16, vTbuf, qt16, fmat, table_v, tvTbuf, xb16);

    GemmArgs go = {};
    go.A[0] = xb16; go.W[0] = wo16; go.bias[0] = bo;
    go.Cf[0] = (float*)d_out; go.Cb[0] = nullptr;
    gemm_bf16<<<dim3(HID / 128, M / 128, 1), 256, 0, stream>>>(go, M, HID, HID);
}

// Round 11
// 191.980 us; speedup vs baseline: 2.5953x; 1.1970x over previous
//
#include <hip/hip_runtime.h>

#define HID 1024
#define HEADS 16
#define HD 64
#define TAB 129
#define QSTR 136   // padded qtab row stride (ushorts, 16B-aligned rows)
#define BATCH 8
#define SEQ 512

typedef unsigned int uint;
typedef unsigned short ushort;
typedef __attribute__((ext_vector_type(4))) float f32x4;
typedef __attribute__((ext_vector_type(8))) __bf16 bf16x8;

// ---------------------------------------------------------------------------
// bf16 helpers
// ---------------------------------------------------------------------------
__device__ __forceinline__ ushort f2b(float x) {
    uint b = __float_as_uint(x);
    uint r = (b + 0x7fffu + ((b >> 16) & 1u)) >> 16;
    return (ushort)r;
}
__device__ __forceinline__ uint pk(float lo, float hi) {
    return (uint)f2b(lo) | ((uint)f2b(hi) << 16);
}
__device__ __forceinline__ float b2f(ushort u) {
    return __uint_as_float(((uint)u) << 16);
}
union U16x8 { uint u[4]; bf16x8 v; ushort s[8]; uint4 q; };
__device__ __forceinline__ bf16x8 pack8(float a0, float a1, float a2, float a3,
                                        float a4, float a5, float a6, float a7) {
    U16x8 r;
    r.u[0] = pk(a0, a1); r.u[1] = pk(a2, a3);
    r.u[2] = pk(a4, a5); r.u[3] = pk(a6, a7);
    return r.v;
}

#define GL16(gp, lp) __builtin_amdgcn_global_load_lds( \
    (const __attribute__((address_space(1))) void*)(gp), \
    (__attribute__((address_space(3))) void*)(lp), 16, 0, 0)

// LDS-only barrier: order DS ops, keep in-flight VMEM alive
#define LDS_BARRIER() do { \
        asm volatile("s_waitcnt lgkmcnt(0)" ::: "memory"); \
        __builtin_amdgcn_s_barrier(); \
    } while (0)

// ---------------------------------------------------------------------------
// convert fp32 -> bf16
// ---------------------------------------------------------------------------
struct ConvArgs { const float* src[7]; ushort* dst[7]; };

__global__ __launch_bounds__(256) void convert_bf16(ConvArgs ca) {
    int bid = blockIdx.x;
    int ti, lb;
    if (bid < 6144) { ti = bid >> 11; lb = bid & 2047; }
    else { int r = bid - 6144; ti = 3 + (r >> 9); lb = r & 511; }
    const float* s = ca.src[ti] + (size_t)lb * 2048 + (threadIdx.x << 3);
    ushort*      d = ca.dst[ti] + (size_t)lb * 2048 + (threadIdx.x << 3);
    float4 a = *(const float4*)s;
    float4 c = *(const float4*)(s + 4);
    uint4 u;
    u.x = pk(a.x, a.y); u.y = pk(a.z, a.w);
    u.z = pk(c.x, c.y); u.w = pk(c.z, c.w);
    *(uint4*)d = u;
}

// ---------------------------------------------------------------------------
// bf16 MFMA GEMM (QKV, unchanged): C_z = A_z @ W_z^T + bias_z
// ---------------------------------------------------------------------------
struct GemmArgs {
    const ushort* A[3];
    const ushort* W[3];
    const float*  bias[3];
    float*        Cf[3];
    ushort*       Cb[3];
};

__global__ __launch_bounds__(256) void gemm_bf16(GemmArgs ga, int M, int N, int K) {
    __shared__ ushort As[2][128 * 32];
    __shared__ ushort Bs[2][128 * 32];
    const int z = blockIdx.z;
    const ushort* A = ga.A[z];
    const ushort* W = ga.W[z];
    const int tid = threadIdx.x;
    const int m0 = blockIdx.y * 128;
    const int n0 = blockIdx.x * 128;

    const int w  = tid >> 6;
    const int l  = tid & 63;
    const int lr = l & 15;
    const int lg = l >> 4;
    const int wm = w >> 1;
    const int wn = w & 1;

    const int sr = tid >> 2;
    const int sc = tid & 3;
    const int g  = sc ^ ((sr >> 1) & 3);
    const ushort* Ag0 = A + (size_t)(m0 + sr)      * K + g * 8;
    const ushort* Ag1 = A + (size_t)(m0 + sr + 64) * K + g * 8;
    const ushort* Wg0 = W + (size_t)(n0 + sr)      * K + g * 8;
    const ushort* Wg1 = W + (size_t)(n0 + sr + 64) * K + g * 8;

    f32x4 acc[4][4];
#pragma unroll
    for (int mt = 0; mt < 4; ++mt)
#pragma unroll
        for (int nt = 0; nt < 4; ++nt) acc[mt][nt] = (f32x4){0.f, 0.f, 0.f, 0.f};

#define STAGE(buf, k0) do { \
        GL16(Ag0 + (k0), &As[buf][w * 512]); \
        GL16(Ag1 + (k0), &As[buf][2048 + w * 512]); \
        GL16(Wg0 + (k0), &Bs[buf][w * 512]); \
        GL16(Wg1 + (k0), &Bs[buf][2048 + w * 512]); \
    } while (0)

    const int swz = (lr >> 1) & 3;
#define COMPUTE(buf) do { \
        bf16x8 af[4], bf[4]; \
        _Pragma("unroll") \
        for (int mt = 0; mt < 4; ++mt) \
            af[mt] = *(const bf16x8*)&As[buf][(wm * 64 + mt * 16 + lr) * 32 + (lg ^ swz) * 8]; \
        _Pragma("unroll") \
        for (int nt = 0; nt < 4; ++nt) \
            bf[nt] = *(const bf16x8*)&Bs[buf][(wn * 64 + nt * 16 + lr) * 32 + (lg ^ swz) * 8]; \
        _Pragma("unroll") \
        for (int mt = 0; mt < 4; ++mt) \
            _Pragma("unroll") \
            for (int nt = 0; nt < 4; ++nt) \
                acc[mt][nt] = __builtin_amdgcn_mfma_f32_16x16x32_bf16(af[mt], bf[nt], acc[mt][nt], 0, 0, 0); \
    } while (0)

    STAGE(0, 0);
    __syncthreads();
    const int nk = K / 32;
    for (int t = 0; t < nk - 1; ++t) {
        STAGE((t + 1) & 1, (size_t)(t + 1) * 32);
        COMPUTE(t & 1);
        __syncthreads();
    }
    COMPUTE((nk - 1) & 1);

    const float* bias = ga.bias[z];
    float bv[4];
#pragma unroll
    for (int nt = 0; nt < 4; ++nt) bv[nt] = bias[n0 + wn * 64 + nt * 16 + lr];
    float*  Cf = ga.Cf[z];
    ushort* Cb = ga.Cb[z];
    if (Cf) {
#pragma unroll
        for (int mt = 0; mt < 4; ++mt)
#pragma unroll
            for (int r4 = 0; r4 < 4; ++r4) {
                size_t m = m0 + wm * 64 + mt * 16 + lg * 4 + r4;
                float* crow = Cf + m * N + n0 + wn * 64 + lr;
#pragma unroll
                for (int nt = 0; nt < 4; ++nt)
                    crow[nt * 16] = acc[mt][nt][r4] + bv[nt];
            }
    } else {
#pragma unroll
        for (int mt = 0; mt < 4; ++mt)
#pragma unroll
            for (int r4 = 0; r4 < 4; ++r4) {
                size_t m = m0 + wm * 64 + mt * 16 + lg * 4 + r4;
                ushort* crow = Cb + m * N + n0 + wn * 64 + lr;
#pragma unroll
                for (int nt = 0; nt < 4; ++nt)
                    crow[nt * 16] = f2b(acc[mt][nt][r4] + bv[nt]);
            }
    }
#undef STAGE
#undef COMPUTE
}

// ---------------------------------------------------------------------------
// Wo GEMM, BN=64 tile (512 blocks -> 2 blocks/CU): C = A @ W^T + bias, fp32 out
// ---------------------------------------------------------------------------
__global__ __launch_bounds__(256) void gemm_wo(const ushort* __restrict__ A,
                                               const ushort* __restrict__ W,
                                               const float* __restrict__ bias,
                                               float* __restrict__ Cf) {
    const int M = BATCH * SEQ, N = HID, K = HID;
    __shared__ ushort As[2][128 * 32];
    __shared__ ushort Bs[2][64 * 32];
    const int tid = threadIdx.x;
    const int m0 = blockIdx.y * 128;
    const int n0 = blockIdx.x * 64;

    const int w  = tid >> 6;
    const int l  = tid & 63;
    const int lr = l & 15;
    const int lg = l >> 4;
    const int wm = w >> 1;       // m-half (64 rows)
    const int wn = w & 1;        // n-half (32 cols)

    const int sr = tid >> 2;
    const int sc = tid & 3;
    const int g  = sc ^ ((sr >> 1) & 3);
    const ushort* Ag0 = A + (size_t)(m0 + sr)      * K + g * 8;
    const ushort* Ag1 = A + (size_t)(m0 + sr + 64) * K + g * 8;
    const ushort* Wg0 = W + (size_t)(n0 + sr)      * K + g * 8;

    f32x4 acc[4][2];
#pragma unroll
    for (int mt = 0; mt < 4; ++mt)
#pragma unroll
        for (int nt = 0; nt < 2; ++nt) acc[mt][nt] = (f32x4){0.f, 0.f, 0.f, 0.f};

#define STAGE(buf, k0) do { \
        GL16(Ag0 + (k0), &As[buf][w * 512]); \
        GL16(Ag1 + (k0), &As[buf][2048 + w * 512]); \
        GL16(Wg0 + (k0), &Bs[buf][w * 512]); \
    } while (0)

    const int swz = (lr >> 1) & 3;
#define COMPUTE(buf) do { \
        bf16x8 af[4], bf[2]; \
        _Pragma("unroll") \
        for (int mt = 0; mt < 4; ++mt) \
            af[mt] = *(const bf16x8*)&As[buf][(wm * 64 + mt * 16 + lr) * 32 + (lg ^ swz) * 8]; \
        _Pragma("unroll") \
        for (int nt = 0; nt < 2; ++nt) \
            bf[nt] = *(const bf16x8*)&Bs[buf][(wn * 32 + nt * 16 + lr) * 32 + (lg ^ swz) * 8]; \
        _Pragma("unroll") \
        for (int mt = 0; mt < 4; ++mt) \
            _Pragma("unroll") \
            for (int nt = 0; nt < 2; ++nt) \
                acc[mt][nt] = __builtin_amdgcn_mfma_f32_16x16x32_bf16(af[mt], bf[nt], acc[mt][nt], 0, 0, 0); \
    } while (0)

    STAGE(0, 0);
    __syncthreads();
    const int nk = K / 32;
    for (int t = 0; t < nk - 1; ++t) {
        STAGE((t + 1) & 1, (size_t)(t + 1) * 32);
        COMPUTE(t & 1);
        __syncthreads();
    }
    COMPUTE((nk - 1) & 1);

    float bv[2];
#pragma unroll
    for (int nt = 0; nt < 2; ++nt) bv[nt] = bias[n0 + wn * 32 + nt * 16 + lr];
#pragma unroll
    for (int mt = 0; mt < 4; ++mt)
#pragma unroll
        for (int r4 = 0; r4 < 4; ++r4) {
            size_t m = m0 + wm * 64 + mt * 16 + lg * 4 + r4;
            float* crow = Cf + m * N + n0 + wn * 32 + lr;
#pragma unroll
            for (int nt = 0; nt < 2; ++nt)
                crow[nt * 16] = acc[mt][nt][r4] + bv[nt];
        }
#undef STAGE
#undef COMPUTE
}

// ---------------------------------------------------------------------------
// prep_kernel: fused qtab (MFMA) + V-transpose + tvT build.
//  blocks 0..255   : qtab[b,h,q,t] = q4[b,q,h,:] . table_k[t,:]  via MFMA
//                    (block = (b,h,half-of-512-q); wave = 64 q rows)
//  blocks 256..767 : vT[b,h,d,k] transpose of projected V
//  block  768      : tvT[d][t] = table_v^T (bf16)
// ---------------------------------------------------------------------------
__global__ __launch_bounds__(256) void prep_kernel(const ushort* __restrict__ qb,
                                                   const float* __restrict__ table_k,
                                                   const ushort* __restrict__ vb,
                                                   const float* __restrict__ table_v,
                                                   ushort* __restrict__ qtab,
                                                   ushort* __restrict__ vT,
                                                   ushort* __restrict__ tvT) {
    __shared__ __align__(16) ushort shmem[144 * 72];   // 20,736 B
    const int wg  = blockIdx.x;
    const int tid = threadIdx.x;

    if (wg < 256) {
        // ---- qtab via MFMA: A = table_k rows (t), B = q rows -> C[t][q] ----
        const int h    = wg & 15;
        const int half = (wg >> 4) & 1;
        const int b    = wg >> 5;
        const int q0   = half * 256;
        ushort* tk = shmem;                            // [144][72] bf16
        for (int i = tid; i < TAB * 8; i += 256) {     // 129 rows x 8 granules
            int row = i >> 3, gr = i & 7;
            const float* src = table_k + row * HD + gr * 8;
            float4 a = *(const float4*)src;
            float4 c = *(const float4*)(src + 4);
            uint4 u;
            u.x = pk(a.x, a.y); u.y = pk(a.z, a.w);
            u.z = pk(c.x, c.y); u.w = pk(c.z, c.w);
            *(uint4*)&tk[row * 72 + gr * 8] = u;
        }
        __syncthreads();

        const int w  = tid >> 6;                       // wave -> 64 q rows
        const int l  = tid & 63;
        const int lr = l & 15;
        const int lg = l >> 4;
        bf16x8 qf[4][2];
#pragma unroll
        for (int qt = 0; qt < 4; ++qt) {
            const ushort* qrow = qb + ((size_t)(b * SEQ) + q0 + w * 64 + qt * 16 + lr) * HID + h * HD;
            qf[qt][0] = *(const bf16x8*)(qrow + lg * 8);
            qf[qt][1] = *(const bf16x8*)(qrow + 32 + lg * 8);
        }
        ushort* outbase = qtab + ((size_t)(b * HEADS + h) * SEQ + q0 + w * 64) * QSTR;
#pragma unroll
        for (int mt = 0; mt < 9; ++mt) {
            bf16x8 tf0 = *(const bf16x8*)&tk[(mt * 16 + lr) * 72 + lg * 8];
            bf16x8 tf1 = *(const bf16x8*)&tk[(mt * 16 + lr) * 72 + 32 + lg * 8];
#pragma unroll
            for (int qt = 0; qt < 4; ++qt) {
                f32x4 acc = (f32x4){0.f, 0.f, 0.f, 0.f};
                acc = __builtin_amdgcn_mfma_f32_16x16x32_bf16(tf0, qf[qt][0], acc, 0, 0, 0);
                acc = __builtin_amdgcn_mfma_f32_16x16x32_bf16(tf1, qf[qt][1], acc, 0, 0, 0);
                ushort* orow = outbase + (size_t)(qt * 16 + lr) * QSTR;
                if (mt < 8) {
                    uint2 pu;
                    pu.x = pk(acc[0], acc[1]); pu.y = pk(acc[2], acc[3]);
                    *(uint2*)&orow[mt * 16 + lg * 4] = pu;   // t = mt*16+4lg+r
                } else if (lg == 0) {
                    orow[128] = f2b(acc[0]);                 // t = 128 tail
                }
            }
        }
    } else if (wg < 768) {
        // ---- V transpose ----
        const int vw = wg - 256;
        ushort* tile = shmem;                          // [128][72]
        const int b = vw >> 6, h = (vw >> 2) & 15, kc = vw & 3;
        const int k0 = kc * 128;
        {
            const int kr = tid >> 1, dc = (tid & 1) * 32;
            const ushort* src = vb + ((size_t)(b * SEQ) + k0 + kr) * HID + h * 64 + dc;
#pragma unroll
            for (int j = 0; j < 4; ++j) {
                uint4 u = *(const uint4*)(src + j * 8);
                *(uint4*)&tile[kr * 72 + dc + j * 8] = u;
            }
        }
        __syncthreads();
        {
            const int dr = tid >> 2, kc2 = (tid & 3) * 32;
            ushort* dst = vT + ((size_t)(b * 16 + h) * 64 + dr) * 512 + k0 + kc2;
#pragma unroll
            for (int j = 0; j < 4; ++j) {
                U16x8 o;
#pragma unroll
                for (int i = 0; i < 8; ++i)
                    o.s[i] = tile[(kc2 + j * 8 + i) * 72 + dr];
                *(uint4*)(dst + j * 8) = o.q;
            }
        }
    } else {
        // ---- tvT ----
        const int tt = tid >> 1, dc = (tid & 1) * 32;
        const float* src = table_v + (size_t)tt * HD + dc;
#pragma unroll
        for (int i = 0; i < 32; ++i)
            tvT[(size_t)(dc + i) * 128 + tt] = f2b(src[i]);
    }
}

// ---------------------------------------------------------------------------
// Fused attention (R10 structure, unchanged): k-split 4 waves x 2 k-tiles,
// fixed-point ds_add_u32 bins, split load/compute phase 1.
// ---------------------------------------------------------------------------
__global__ __launch_bounds__(256, 3) void attn_mfma(const ushort* __restrict__ qp,
                                                    const ushort* __restrict__ kp,
                                                    const ushort* __restrict__ vT,
                                                    const ushort* __restrict__ qt,
                                                    const int* __restrict__ fmat,
                                                    const float* __restrict__ table_v,
                                                    const ushort* __restrict__ tvT,
                                                    ushort* __restrict__ x) {
    constexpr float FIX = 65536.0f;
    constexpr float INV_FIX = 1.0f / 65536.0f;

    __shared__ __align__(16) ushort qtb[16 * QSTR];    //  4,352 B
    __shared__ __align__(16) uint   sbin[16 * 132];    //  8,448 B (fixed-point)
    __shared__ __align__(16) ushort P[4][16 * 136];    // 17,408 B (later: obuf f32)
    __shared__ float rowsumw[4][16];                   //    256 B

    const int tid = threadIdx.x;
    const int w   = tid >> 6;         // wave 0..3 -> k-tiles {2w, 2w+1}
    const int l   = tid & 63;
    const int lr  = l & 15;
    const int lg  = l >> 4;

    const int wg   = blockIdx.x;
    const int work = (wg & 7) * 512 + (wg >> 3);
    const int qblk = work & 31;
    const int h    = (work >> 5) & 15;
    const int b    = work >> 9;
    const int q0   = qblk * 16;
    const size_t bSEQ = (size_t)b * SEQ;
    const int hHD = h * HD;

    const int*    fmrow    = fmat + (bSEQ + q0 + lr) * SEQ;
    const ushort* kfr_base = kp + (bSEQ + lr) * HID + hHD;
    const ushort* vfr_base = vT + ((size_t)(b * HEADS + h) * HD + lr) * SEQ;

    bf16x8 qfrag[2];
    {
        const ushort* qrow = qp + (bSEQ + q0 + lr) * HID + hHD;
        qfrag[0] = *(const bf16x8*)(qrow + lg * 8);
        qfrag[1] = *(const bf16x8*)(qrow + 32 + lg * 8);
    }

    // ---- prologue: stage qtab rows, zero bins ----
    {
        const uint4* src = (const uint4*)(qt + ((size_t)(b * HEADS + h) * SEQ + q0) * QSTR);
        uint4* dst = (uint4*)qtb;
        for (int i = tid; i < 16 * QSTR / 8; i += 256) dst[i] = src[i];
    }
    {
        uint4 z = {0u, 0u, 0u, 0u};
        uint4* dz = (uint4*)sbin;
        for (int i = tid; i < 16 * 132 / 4; i += 256) dz[i] = z;
    }
    LDS_BARRIER();                                     // sync1

    // ---- Phase 1a: pure {K/fm load + MFMA} stream ----
    f32x4 stv[8];
    int4  fmr[8];
#pragma unroll
    for (int i = 0; i < 8; ++i) {
        const int t  = i >> 2;
        const int mt = i & 3;
        const int k0 = (w * 2 + t) * 64;
        const ushort* kr = kfr_base + (size_t)(k0 + mt * 16) * HID;
        bf16x8 ka0 = *(const bf16x8*)(kr + lg * 8);
        bf16x8 ka1 = *(const bf16x8*)(kr + 32 + lg * 8);
        fmr[i] = *(const int4*)&fmrow[k0 + mt * 16 + lg * 4];
        f32x4 st = (f32x4){0.f, 0.f, 0.f, 0.f};
        st = __builtin_amdgcn_mfma_f32_16x16x32_bf16(ka0, qfrag[0], st, 0, 0, 0);
        st = __builtin_amdgcn_mfma_f32_16x16x32_bf16(ka1, qfrag[1], st, 0, 0, 0);
        stv[i] = st;
    }

    // ---- Phase 1b: gather + exp + bins (u32 fixed-point) + P ----
    float lsum = 0.f;
#pragma unroll
    for (int i = 0; i < 8; ++i) {
        const int t  = i >> 2;
        const int mt = i & 3;
        const int4 fm4 = fmr[i];
        const f32x4 st = stv[i];
        float pr0 = __expf((st[0] + b2f(qtb[lr * QSTR + fm4.x])) * 0.125f);
        float pr1 = __expf((st[1] + b2f(qtb[lr * QSTR + fm4.y])) * 0.125f);
        float pr2 = __expf((st[2] + b2f(qtb[lr * QSTR + fm4.z])) * 0.125f);
        float pr3 = __expf((st[3] + b2f(qtb[lr * QSTR + fm4.w])) * 0.125f);
        lsum += pr0 + pr1 + pr2 + pr3;
        __hip_atomic_fetch_add(&sbin[lr * 132 + fm4.x], (uint)(pr0 * FIX),
                               __ATOMIC_RELAXED, __HIP_MEMORY_SCOPE_WORKGROUP);
        __hip_atomic_fetch_add(&sbin[lr * 132 + fm4.y], (uint)(pr1 * FIX),
                               __ATOMIC_RELAXED, __HIP_MEMORY_SCOPE_WORKGROUP);
        __hip_atomic_fetch_add(&sbin[lr * 132 + fm4.z], (uint)(pr2 * FIX),
                               __ATOMIC_RELAXED, __HIP_MEMORY_SCOPE_WORKGROUP);
        __hip_atomic_fetch_add(&sbin[lr * 132 + fm4.w], (uint)(pr3 * FIX),
                               __ATOMIC_RELAXED, __HIP_MEMORY_SCOPE_WORKGROUP);
        uint2 pu;
        pu.x = pk(pr0, pr1); pu.y = pk(pr2, pr3);
        *(uint2*)&P[w][lr * 136 + t * 64 + mt * 16 + lg * 4] = pu;
    }
    lsum += __shfl_xor(lsum, 16);
    lsum += __shfl_xor(lsum, 32);
    if (lg == 0) rowsumw[w][lr] = lsum;

    // ---- PV (own-wave P; V-frag loads pipeline across MFMAs) ----
    f32x4 acc_o[4];
#pragma unroll
    for (int nt = 0; nt < 4; ++nt) acc_o[nt] = (f32x4){0.f, 0.f, 0.f, 0.f};
#pragma unroll
    for (int t = 0; t < 2; ++t) {
        const int k0 = (w * 2 + t) * 64;
        bf16x8 pa0 = *(const bf16x8*)&P[w][lr * 136 + t * 64 + lg * 8];
        bf16x8 pa1 = *(const bf16x8*)&P[w][lr * 136 + t * 64 + 32 + lg * 8];
#pragma unroll
        for (int nt = 0; nt < 4; ++nt) {
            const ushort* vr = vfr_base + (size_t)nt * 16 * SEQ + k0;
            bf16x8 vb0 = *(const bf16x8*)(vr + lg * 8);
            bf16x8 vb1 = *(const bf16x8*)(vr + 32 + lg * 8);
            acc_o[nt] = __builtin_amdgcn_mfma_f32_16x16x32_bf16(pa0, vb0, acc_o[nt], 0, 0, 0);
            acc_o[nt] = __builtin_amdgcn_mfma_f32_16x16x32_bf16(pa1, vb1, acc_o[nt], 0, 0, 0);
        }
    }

    LDS_BARRIER();                                     // sync2: bins done, P dead

    // ---- w2 slice: t-range [w*32, w*32+32) ----
    {
        const uint* sp = &sbin[lr * 132 + w * 32 + lg * 8];
        bf16x8 af = pack8((float)sp[0] * INV_FIX, (float)sp[1] * INV_FIX,
                          (float)sp[2] * INV_FIX, (float)sp[3] * INV_FIX,
                          (float)sp[4] * INV_FIX, (float)sp[5] * INV_FIX,
                          (float)sp[6] * INV_FIX, (float)sp[7] * INV_FIX);
#pragma unroll
        for (int nt = 0; nt < 4; ++nt) {
            bf16x8 bf_ = *(const bf16x8*)(tvT + (size_t)(nt * 16 + lr) * 128 + w * 32 + lg * 8);
            acc_o[nt] = __builtin_amdgcn_mfma_f32_16x16x32_bf16(af, bf_, acc_o[nt], 0, 0, 0);
        }
    }

    // ---- cross-wave O reduction through dead P region ----
    float* obuf = (float*)&P[0][0];
    if (w != 0) {
#pragma unroll
        for (int nt = 0; nt < 4; ++nt)
            *(f32x4*)&obuf[(((w - 1) * 4 + nt) * 64 + l) * 4] = acc_o[nt];
    }
    LDS_BARRIER();                                     // sync3

    if (w == 0) {
#pragma unroll
        for (int j = 0; j < 3; ++j)
#pragma unroll
            for (int nt = 0; nt < 4; ++nt) {
                f32x4 p_ = *(const f32x4*)&obuf[((j * 4 + nt) * 64 + l) * 4];
                acc_o[nt][0] += p_[0]; acc_o[nt][1] += p_[1];
                acc_o[nt][2] += p_[2]; acc_o[nt][3] += p_[3];
            }
        float iv[4], nb[4];
#pragma unroll
        for (int r = 0; r < 4; ++r) {
            const int q = lg * 4 + r;
            iv[r] = 1.f / (rowsumw[0][q] + rowsumw[1][q] + rowsumw[2][q] + rowsumw[3][q]);
            nb[r] = (float)sbin[q * 132 + 128] * INV_FIX;   // t=128 tail bin
        }
        ushort* orow = x + (bSEQ + q0 + lg * 4) * HID + hHD;
#pragma unroll
        for (int nt = 0; nt < 4; ++nt) {
            float tv = table_v[(size_t)128 * HD + nt * 16 + lr];
#pragma unroll
            for (int r = 0; r < 4; ++r) {
                float o = (acc_o[nt][r] + nb[r] * tv) * iv[r];
                orow[(size_t)r * HID + nt * 16 + lr] = f2b(o);
            }
        }
    }
}

// ---------------------------------------------------------------------------
extern "C" void kernel_launch(void* const* d_in, const int* in_sizes, int n_in,
                              void* d_out, int out_size, void* d_ws, size_t ws_size,
                              hipStream_t stream) {
    const float* query = (const float*)d_in[0];
    const float* key   = (const float*)d_in[1];
    const float* value = (const float*)d_in[2];
    const int*   fmat  = (const int*)d_in[3];
    const float* Wq = (const float*)d_in[4];
    const float* bq = (const float*)d_in[5];
    const float* Wk = (const float*)d_in[6];
    const float* bk = (const float*)d_in[7];
    const float* Wv = (const float*)d_in[8];
    const float* bv = (const float*)d_in[9];
    const float* Wo = (const float*)d_in[10];
    const float* bo = (const float*)d_in[11];
    const float* table_k = (const float*)d_in[12];
    const float* table_v = (const float*)d_in[13];

    const size_t nBLD = (size_t)BATCH * SEQ * HID;   // 4,194,304
    const size_t nW   = (size_t)HID * HID;           // 1,048,576
    ushort* us = (ushort*)d_ws;
    ushort* qin16 = us;                 us += nBLD;   // later reused as vT
    ushort* kin16 = us;                 us += nBLD;   // later reused as tvT
    ushort* vin16 = us;                 us += nBLD;
    ushort* wq16  = us;                 us += nW;
    ushort* wk16  = us;                 us += nW;
    ushort* wv16  = us;                 us += nW;
    ushort* wo16  = us;                 us += nW;
    ushort* qb16  = us;                 us += nBLD;
    ushort* kb16  = us;                 us += nBLD;
    ushort* vb16  = us;                 us += nBLD;
    ushort* qt16  = us;                 us += (size_t)BATCH * HEADS * SEQ * QSTR;
    ushort* xb16  = us;                 us += nBLD;

    ConvArgs ca;
    ca.src[0] = query; ca.src[1] = key; ca.src[2] = value;
    ca.src[3] = Wq; ca.src[4] = Wk; ca.src[5] = Wv; ca.src[6] = Wo;
    ca.dst[0] = qin16; ca.dst[1] = kin16; ca.dst[2] = vin16;
    ca.dst[3] = wq16; ca.dst[4] = wk16; ca.dst[5] = wv16; ca.dst[6] = wo16;
    convert_bf16<<<dim3(8192), 256, 0, stream>>>(ca);

    const int M = BATCH * SEQ;  // 4096

    GemmArgs gq = {};
    gq.A[0] = qin16; gq.A[1] = kin16; gq.A[2] = vin16;
    gq.W[0] = wq16;  gq.W[1] = wk16;  gq.W[2] = wv16;
    gq.bias[0] = bq; gq.bias[1] = bk; gq.bias[2] = bv;
    gq.Cf[0] = nullptr; gq.Cf[1] = nullptr; gq.Cf[2] = nullptr;
    gq.Cb[0] = qb16; gq.Cb[1] = kb16; gq.Cb[2] = vb16;
    gemm_bf16<<<dim3(HID / 128, M / 128, 3), 256, 0, stream>>>(gq, M, HID, HID);

    // qin16/kin16 are dead after the QKV GEMM: reuse as vT / tvT
    ushort* vTbuf  = qin16;   // [B,H,64,512] bf16
    ushort* tvTbuf = kin16;   // [64,128] bf16

    // fused: qtab (MFMA, blocks 0..255) + V transpose (256..767) + tvT (768)
    prep_kernel<<<dim3(769), 256, 0, stream>>>(qb16, table_k, vb16, table_v,
                                               qt16, vTbuf, tvTbuf);

    attn_mfma<<<dim3(BATCH * HEADS * (SEQ/16)), 256, 0, stream>>>(
        qb16, kb16, vTbuf, qt16, fmat, table_v, tvTbuf, xb16);

    gemm_wo<<<dim3(HID / 64, M / 128), 256, 0, stream>>>(xb16, wo16, bo, (float*)d_out);
}